// Round 1
// baseline (610.434 us; speedup 1.0000x reference)
//
#include <hip/hip_runtime.h>
#include <hip/hip_bf16.h>
#include <cstdint>

#define VOCAB 50000
#define EMB   300
#define SEQ   80
#define HID   128
#define BATCH 4096

static __device__ __forceinline__ unsigned short f32_to_bf16(float f) {
    unsigned int u = __float_as_uint(f);
    unsigned int r = 0x7FFFu + ((u >> 16) & 1u);
    return (unsigned short)((u + r) >> 16);
}
static __device__ __forceinline__ float bf16_to_f32(unsigned short s) {
    return __uint_as_float(((unsigned int)s) << 16);
}

// ---------------------------------------------------------------------------
// Kernel 1: xp[t][b][h] (bf16) = emb[x[b][t]] @ Wxh + bh   (fp32 compute)
// M = BATCH*SEQ rows (row m = b*SEQ + t), K = EMB = 300, N = HID = 128.
// Block: 256 threads, TILE_M = 64 rows, full N, K staged in 5 chunks of 60.
// Thread owns 8 rows x 4 cols: per k, 2x b128 (e) + 1x b128 (W) -> 32 FMA.
// ---------------------------------------------------------------------------
#define K1_TM 64
#define K1_KC 60

__global__ __launch_bounds__(256, 2) void k_xproj(
    const int*   __restrict__ x,    // [BATCH*SEQ]
    const float* __restrict__ emb,  // [VOCAB][EMB]
    const float* __restrict__ Wxh,  // [EMB][HID]
    const float* __restrict__ bh,   // [HID]
    unsigned short* __restrict__ xp // [SEQ][BATCH][HID] bf16
)
{
    __shared__ __align__(16) float et[K1_KC][K1_TM];  // e transposed [k][row]
    __shared__ __align__(16) float wt[K1_KC][HID];    // Wxh chunk    [k][col]
    __shared__ int rowidx[K1_TM];

    const int tid = threadIdx.x;
    const int m0  = blockIdx.x * K1_TM;

    if (tid < K1_TM) rowidx[tid] = x[m0 + tid];  // flat index m = b*SEQ + t
    __syncthreads();

    const int r0 = (tid >> 5) * 8;   // 0,8,...,56
    const int c0 = (tid & 31) * 4;   // 0,4,...,124

    float acc[8][4];
    #pragma unroll
    for (int r = 0; r < 8; ++r)
        #pragma unroll
        for (int c = 0; c < 4; ++c) acc[r][c] = 0.f;

    for (int kc = 0; kc < EMB / K1_KC; ++kc) {
        const int kbase = kc * K1_KC;

        // stage gathered embedding rows, transposed: 64 rows x 15 float4
        for (int q = tid; q < K1_TM * (K1_KC / 4); q += 256) {
            const int r = q / (K1_KC / 4);
            const int f = q % (K1_KC / 4);
            const float4 v = *reinterpret_cast<const float4*>(
                &emb[(size_t)rowidx[r] * EMB + kbase + f * 4]);
            et[f * 4 + 0][r] = v.x;
            et[f * 4 + 1][r] = v.y;
            et[f * 4 + 2][r] = v.z;
            et[f * 4 + 3][r] = v.w;
        }
        // stage Wxh chunk: 60 rows x 32 float4 (natural layout)
        for (int q = tid; q < K1_KC * (HID / 4); q += 256) {
            const int kk = q >> 5;
            const int f  = q & 31;
            *reinterpret_cast<float4*>(&wt[kk][f * 4]) =
                *reinterpret_cast<const float4*>(&Wxh[(size_t)(kbase + kk) * HID + f * 4]);
        }
        __syncthreads();

        #pragma unroll 4
        for (int kk = 0; kk < K1_KC; ++kk) {
            const float4 alo = *reinterpret_cast<const float4*>(&et[kk][r0]);
            const float4 ahi = *reinterpret_cast<const float4*>(&et[kk][r0 + 4]);
            const float4 w4  = *reinterpret_cast<const float4*>(&wt[kk][c0]);
            const float a[8] = {alo.x, alo.y, alo.z, alo.w, ahi.x, ahi.y, ahi.z, ahi.w};
            #pragma unroll
            for (int r = 0; r < 8; ++r) {
                acc[r][0] = fmaf(a[r], w4.x, acc[r][0]);
                acc[r][1] = fmaf(a[r], w4.y, acc[r][1]);
                acc[r][2] = fmaf(a[r], w4.z, acc[r][2]);
                acc[r][3] = fmaf(a[r], w4.w, acc[r][3]);
            }
        }
        __syncthreads();
    }

    const float4 bv = *reinterpret_cast<const float4*>(&bh[c0]);
    #pragma unroll
    for (int r = 0; r < 8; ++r) {
        const int m = m0 + r0 + r;
        const int b = m / SEQ;
        const int t = m % SEQ;
        ushort4 o;
        o.x = f32_to_bf16(acc[r][0] + bv.x);
        o.y = f32_to_bf16(acc[r][1] + bv.y);
        o.z = f32_to_bf16(acc[r][2] + bv.z);
        o.w = f32_to_bf16(acc[r][3] + bv.w);
        *reinterpret_cast<ushort4*>(&xp[((size_t)t * BATCH + b) * HID + c0]) = o;
    }
}

// ---------------------------------------------------------------------------
// Kernel 2: 80-step tanh recurrence + fused final dense+sigmoid.
// Block: 256 threads owns ROWS=16 batch rows for ALL timesteps (batch rows
// independent -> no grid sync). Whh staged in LDS (64 KB), h in LDS (8 KB).
// Thread owns 2 rows x 4 cols of h_new.
// ---------------------------------------------------------------------------
#define K2_ROWS 16

__global__ __launch_bounds__(256, 2) void k_rnn(
    const unsigned short* __restrict__ xp,  // [SEQ][BATCH][HID] bf16
    const float* __restrict__ Whh,          // [HID][HID]
    const float* __restrict__ Wd,           // [HID]
    const float* __restrict__ bd,           // [1]
    float* __restrict__ out                 // [BATCH]
)
{
    __shared__ __align__(16) float w[HID][HID];      // 64 KB
    __shared__ __align__(16) float h[K2_ROWS][HID];  // 8 KB

    const int tid = threadIdx.x;
    const int rb  = blockIdx.x * K2_ROWS;

    // stage Whh (row-major: w[i][j], h_new[j] = sum_i h[i]*w[i][j])
    for (int q = tid; q < (HID * HID) / 4; q += 256) {
        *reinterpret_cast<float4*>(&w[0][0] + (size_t)q * 4) =
            *reinterpret_cast<const float4*>(Whh + (size_t)q * 4);
    }
    // h0 = 0
    for (int q = tid; q < (K2_ROWS * HID) / 4; q += 256) {
        float4 z; z.x = z.y = z.z = z.w = 0.f;
        *reinterpret_cast<float4*>(&h[0][0] + (size_t)q * 4) = z;
    }
    __syncthreads();

    const int c0 = (tid & 31) * 4;    // 0..124
    const int r0 = (tid >> 5) * 2;    // 0,2,...,14

    for (int t = 0; t < SEQ; ++t) {
        float acc[2][4];
        #pragma unroll
        for (int r = 0; r < 2; ++r) {
            const ushort4 u = *reinterpret_cast<const ushort4*>(
                &xp[((size_t)t * BATCH + rb + r0 + r) * HID + c0]);
            acc[r][0] = bf16_to_f32(u.x);
            acc[r][1] = bf16_to_f32(u.y);
            acc[r][2] = bf16_to_f32(u.z);
            acc[r][3] = bf16_to_f32(u.w);
        }

        #pragma unroll 8
        for (int i = 0; i < HID; i += 4) {
            const float4 h0 = *reinterpret_cast<const float4*>(&h[r0][i]);
            const float4 h1 = *reinterpret_cast<const float4*>(&h[r0 + 1][i]);
            const float4 w0 = *reinterpret_cast<const float4*>(&w[i][c0]);
            const float4 w1 = *reinterpret_cast<const float4*>(&w[i + 1][c0]);
            const float4 w2 = *reinterpret_cast<const float4*>(&w[i + 2][c0]);
            const float4 w3 = *reinterpret_cast<const float4*>(&w[i + 3][c0]);
            const float ha[2][4] = {{h0.x, h0.y, h0.z, h0.w},
                                    {h1.x, h1.y, h1.z, h1.w}};
            const float4 wr[4] = {w0, w1, w2, w3};
            #pragma unroll
            for (int r = 0; r < 2; ++r) {
                #pragma unroll
                for (int k = 0; k < 4; ++k) {
                    acc[r][0] = fmaf(ha[r][k], wr[k].x, acc[r][0]);
                    acc[r][1] = fmaf(ha[r][k], wr[k].y, acc[r][1]);
                    acc[r][2] = fmaf(ha[r][k], wr[k].z, acc[r][2]);
                    acc[r][3] = fmaf(ha[r][k], wr[k].w, acc[r][3]);
                }
            }
        }
        __syncthreads();   // all reads of h done before overwrite
        #pragma unroll
        for (int r = 0; r < 2; ++r) {
            float4 o;
            o.x = tanhf(acc[r][0]);
            o.y = tanhf(acc[r][1]);
            o.z = tanhf(acc[r][2]);
            o.w = tanhf(acc[r][3]);
            *reinterpret_cast<float4*>(&h[r0 + r][c0]) = o;
        }
        __syncthreads();   // h_new visible for next step
    }

    // final dense: logit[r] = sum_j h[r][j]*Wd[j] + bd; sigmoid.
    // 16 threads per row (rows 0..15), 8 j's each, shfl-reduce within 16.
    const int r  = tid >> 4;
    const int j0 = (tid & 15) * 8;
    float part = 0.f;
    #pragma unroll
    for (int j = 0; j < 8; ++j) part = fmaf(h[r][j0 + j], Wd[j0 + j], part);
    part += __shfl_down(part, 8, 16);
    part += __shfl_down(part, 4, 16);
    part += __shfl_down(part, 2, 16);
    part += __shfl_down(part, 1, 16);
    if ((tid & 15) == 0) {
        const float z = part + bd[0];
        out[rb + r] = 1.f / (1.f + expf(-z));
    }
}

// ---------------------------------------------------------------------------
extern "C" void kernel_launch(void* const* d_in, const int* in_sizes, int n_in,
                              void* d_out, int out_size, void* d_ws, size_t ws_size,
                              hipStream_t stream)
{
    const int*   x   = (const int*)  d_in[0];
    const float* emb = (const float*)d_in[1];
    const float* Wxh = (const float*)d_in[2];
    const float* Whh = (const float*)d_in[3];
    const float* bh  = (const float*)d_in[4];
    const float* Wd  = (const float*)d_in[5];
    const float* bd  = (const float*)d_in[6];
    float* out = (float*)d_out;

    // workspace: xp as bf16 [SEQ][BATCH][HID] = 80*4096*128*2 B = 84 MB
    unsigned short* xp = (unsigned short*)d_ws;

    k_xproj<<<(BATCH * SEQ) / K1_TM, 256, 0, stream>>>(x, emb, Wxh, bh, xp);
    k_rnn<<<BATCH / K2_ROWS, 256, 0, stream>>>(xp, Whh, Wd, bd, out);
}

// Round 2
// 176.986 us; speedup vs baseline: 3.4490x; 3.4490x over previous
//
#include <hip/hip_runtime.h>
#include <hip/hip_bf16.h>
#include <cstdint>

#define VOCAB 50000
#define EMB   300
#define EMBP  320
#define SEQ   80
#define HID   128
#define BATCH 4096
#define ROWS  16

typedef __attribute__((ext_vector_type(8))) short bf16x8;
typedef __attribute__((ext_vector_type(4))) float f32x4;

static __device__ __forceinline__ unsigned short f32_to_bf16(float f) {
    unsigned int u = __float_as_uint(f);
    unsigned int r = 0x7FFFu + ((u >> 16) & 1u);
    return (unsigned short)((u + r) >> 16);
}
static __device__ __forceinline__ float bf16_to_f32(unsigned short s) {
    return __uint_as_float(((unsigned int)s) << 16);
}

// ---------------------------------------------------------------------------
// k0: emb f32 [VOCAB][300] -> bf16 padded [VOCAB][320] (zeros at k >= 300)
// ---------------------------------------------------------------------------
__global__ __launch_bounds__(256) void k_embcvt(const float* __restrict__ emb,
                                                unsigned short* __restrict__ out) {
    const int gid = blockIdx.x * 256 + threadIdx.x;
    if (gid >= VOCAB * (EMBP / 8)) return;
    const int r  = gid / (EMBP / 8);
    const int kb = gid % (EMBP / 8);
    const int k0 = kb * 8;
    unsigned short res[8] = {0, 0, 0, 0, 0, 0, 0, 0};
    #pragma unroll
    for (int j = 0; j < 8; ++j) {
        if (k0 + j < EMB) res[j] = f32_to_bf16(emb[(size_t)r * EMB + k0 + j]);
    }
    uint4 o;
    o.x = (unsigned)res[0] | ((unsigned)res[1] << 16);
    o.y = (unsigned)res[2] | ((unsigned)res[3] << 16);
    o.z = (unsigned)res[4] | ((unsigned)res[5] << 16);
    o.w = (unsigned)res[6] | ((unsigned)res[7] << 16);
    *reinterpret_cast<uint4*>(out + (size_t)r * EMBP + k0) = o;
}

// ---------------------------------------------------------------------------
// Fused: per block = 16 batch rows for all 80 steps.
//   step t: acc = e_tile(t) @ Wxh  (bf16 MFMA, K=320)
//          + h(t-1) @ Whh          (hi/lo-split bf16 MFMA, K=128, 3 terms)
//   h(t) = tanh(acc + bh) -> LDS (f32, XOR-swizzled)
// Wave w owns output cols [32w, 32w+32): Wxh/Whh fragments live in registers.
// MFMA 16x16x32 conventions (m89/m91-verified):
//   A-frag: lane l holds A[l&15][8*(l>>4)+j], j=0..7
//   B-frag: lane l holds B[8*(l>>4)+j][l&15]
//   C/D:    lane l reg r holds D[4*(l>>4)+r][l&15]
// ---------------------------------------------------------------------------
__global__ __launch_bounds__(256, 1) void k_fused(
    const int*            __restrict__ x,     // [BATCH][SEQ]
    const unsigned short* __restrict__ embb,  // [VOCAB][EMBP] bf16
    const float*          __restrict__ Wxh,   // [EMB][HID]
    const float*          __restrict__ Whh,   // [HID][HID]
    const float*          __restrict__ bh,    // [HID]
    const float*          __restrict__ Wd,    // [HID]
    const float*          __restrict__ bd,    // [1]
    float*                __restrict__ out)   // [BATCH]
{
    __shared__ __align__(16) unsigned char Abuf[2][ROWS * EMBP * 2]; // 2 x 10 KB bf16
    __shared__ __align__(16) float hbuf[ROWS * HID];                 // 8 KB f32
    __shared__ int xidx[ROWS * SEQ];                                 // 5 KB

    const int tid  = threadIdx.x;
    const int lane = tid & 63;
    const int wv   = tid >> 6;     // wave 0..3
    const int r16  = lane & 15;
    const int g    = lane >> 4;    // 0..3
    const int rb   = blockIdx.x * ROWS;

    for (int q = tid; q < ROWS * SEQ; q += 256) xidx[q] = x[rb * SEQ + q];
    for (int q = tid; q < ROWS * HID; q += 256) hbuf[q] = 0.f;

    const int col0 = 32 * wv + r16;
    const int col1 = col0 + 16;

    // ---- register-resident Wxh B-fragments (bf16), K padded to 320 ----
    bf16x8 wx0[10], wx1[10];
    #pragma unroll
    for (int ks = 0; ks < 10; ++ks) {
        bf16x8 f0, f1;
        #pragma unroll
        for (int j = 0; j < 8; ++j) {
            const int kk = 32 * ks + 8 * g + j;
            float v0 = 0.f, v1 = 0.f;
            if (kk < EMB) { v0 = Wxh[kk * HID + col0]; v1 = Wxh[kk * HID + col1]; }
            f0[j] = (short)f32_to_bf16(v0);
            f1[j] = (short)f32_to_bf16(v1);
        }
        wx0[ks] = f0; wx1[ks] = f1;
    }
    // ---- register-resident Whh hi/lo B-fragments ----
    bf16x8 whi0[4], wlo0[4], whi1[4], wlo1[4];
    #pragma unroll
    for (int ks = 0; ks < 4; ++ks) {
        bf16x8 h0, l0, h1, l1;
        #pragma unroll
        for (int j = 0; j < 8; ++j) {
            const int kk = 32 * ks + 8 * g + j;
            const float v0 = Whh[kk * HID + col0];
            const float v1 = Whh[kk * HID + col1];
            const unsigned short u0 = f32_to_bf16(v0);
            const unsigned short u1 = f32_to_bf16(v1);
            h0[j] = (short)u0; l0[j] = (short)f32_to_bf16(v0 - bf16_to_f32(u0));
            h1[j] = (short)u1; l1[j] = (short)f32_to_bf16(v1 - bf16_to_f32(u1));
        }
        whi0[ks] = h0; wlo0[ks] = l0; whi1[ks] = h1; wlo1[ks] = l1;
    }
    const float bhv0 = bh[col0];
    const float bhv1 = bh[col1];

    // ---- gather slot assignment: 640 16B-chunks per A-tile, <=3 per thread ----
    const int q0 = tid, q1 = tid + 256, q2 = tid + 512;
    const int grow0 = q0 / 40, grow1 = q1 / 40, grow2 = q2 / 40;
    const int gdst0 = grow0 * 640 + (((q0 % 40) ^ (grow0 & 7)) * 16);
    const int gdst1 = grow1 * 640 + (((q1 % 40) ^ (grow1 & 7)) * 16);
    const int gdst2 = grow2 * 640 + (((q2 % 40) ^ (grow2 & 7)) * 16);
    const int gso0 = (q0 % 40) * 8, gso1 = (q1 % 40) * 8, gso2 = (q2 % 40) * 8;
    const bool gon2 = (q2 < 640);

    __syncthreads();  // xidx ready

    // stage A-tile for t=0
    {
        const int i0 = xidx[grow0 * SEQ + 0];
        const int i1 = xidx[grow1 * SEQ + 0];
        *reinterpret_cast<uint4*>(&Abuf[0][gdst0]) =
            *reinterpret_cast<const uint4*>(embb + (size_t)i0 * EMBP + gso0);
        *reinterpret_cast<uint4*>(&Abuf[0][gdst1]) =
            *reinterpret_cast<const uint4*>(embb + (size_t)i1 * EMBP + gso1);
        if (gon2) {
            const int i2 = xidx[grow2 * SEQ + 0];
            *reinterpret_cast<uint4*>(&Abuf[0][gdst2]) =
                *reinterpret_cast<const uint4*>(embb + (size_t)i2 * EMBP + gso2);
        }
    }
    __syncthreads();

    const f32x4 z4 = {0.f, 0.f, 0.f, 0.f};
    for (int t = 0; t < SEQ; ++t) {
        const unsigned char* ab = &Abuf[t & 1][0];
        unsigned char*       an = &Abuf[(t & 1) ^ 1][0];

        // issue next-tile gather loads early (latency hides under MFMA)
        uint4 gv0, gv1, gv2;
        const bool pf = (t + 1 < SEQ);
        if (pf) {
            gv0 = *reinterpret_cast<const uint4*>(
                embb + (size_t)xidx[grow0 * SEQ + t + 1] * EMBP + gso0);
            gv1 = *reinterpret_cast<const uint4*>(
                embb + (size_t)xidx[grow1 * SEQ + t + 1] * EMBP + gso1);
            if (gon2) gv2 = *reinterpret_cast<const uint4*>(
                embb + (size_t)xidx[grow2 * SEQ + t + 1] * EMBP + gso2);
        }

        f32x4 acc0 = z4, acc1 = z4;
        // xp contribution: e_tile @ Wxh
        #pragma unroll
        for (int ks = 0; ks < 10; ++ks) {
            const bf16x8 ae = *reinterpret_cast<const bf16x8*>(
                ab + r16 * 640 + (((4 * ks + g) ^ (r16 & 7)) * 16));
            acc0 = __builtin_amdgcn_mfma_f32_16x16x32_bf16(ae, wx0[ks], acc0, 0, 0, 0);
            acc1 = __builtin_amdgcn_mfma_f32_16x16x32_bf16(ae, wx1[ks], acc1, 0, 0, 0);
        }
        // recurrence contribution: h(t-1) @ Whh with hi/lo split
        #pragma unroll
        for (int ks = 0; ks < 4; ++ks) {
            const int cb = 8 * ks + 2 * g;
            const float4 hv0 = *reinterpret_cast<const float4*>(
                (const char*)hbuf + r16 * 512 + ((cb ^ r16) * 16));
            const float4 hv1 = *reinterpret_cast<const float4*>(
                (const char*)hbuf + r16 * 512 + (((cb + 1) ^ r16) * 16));
            const float hv[8] = {hv0.x, hv0.y, hv0.z, hv0.w, hv1.x, hv1.y, hv1.z, hv1.w};
            bf16x8 hh, hl;
            #pragma unroll
            for (int j = 0; j < 8; ++j) {
                const unsigned short us = f32_to_bf16(hv[j]);
                hh[j] = (short)us;
                hl[j] = (short)f32_to_bf16(hv[j] - bf16_to_f32(us));
            }
            acc0 = __builtin_amdgcn_mfma_f32_16x16x32_bf16(hh, whi0[ks], acc0, 0, 0, 0);
            acc0 = __builtin_amdgcn_mfma_f32_16x16x32_bf16(hl, whi0[ks], acc0, 0, 0, 0);
            acc0 = __builtin_amdgcn_mfma_f32_16x16x32_bf16(hh, wlo0[ks], acc0, 0, 0, 0);
            acc1 = __builtin_amdgcn_mfma_f32_16x16x32_bf16(hh, whi1[ks], acc1, 0, 0, 0);
            acc1 = __builtin_amdgcn_mfma_f32_16x16x32_bf16(hl, whi1[ks], acc1, 0, 0, 0);
            acc1 = __builtin_amdgcn_mfma_f32_16x16x32_bf16(hh, wlo1[ks], acc1, 0, 0, 0);
        }
        __syncthreads();  // all h reads done before overwrite

        // h(t) = tanh(acc + bh); D layout: row = 4g+reg, col = lane&15 (+16nf+32w)
        const int cc0 = col0 >> 2, cc1 = col1 >> 2, wb = (col0 & 3) * 4;
        #pragma unroll
        for (int reg = 0; reg < 4; ++reg) {
            const int rr = 4 * g + reg;
            const float v0 = tanhf(acc0[reg] + bhv0);
            const float v1 = tanhf(acc1[reg] + bhv1);
            *reinterpret_cast<float*>((char*)hbuf + rr * 512 + ((cc0 ^ rr) * 16) + wb) = v0;
            *reinterpret_cast<float*>((char*)hbuf + rr * 512 + ((cc1 ^ rr) * 16) + wb) = v1;
        }
        // write prefetched tile (write-late: vmcnt covered by MFMA phase)
        if (pf) {
            *reinterpret_cast<uint4*>(an + gdst0) = gv0;
            *reinterpret_cast<uint4*>(an + gdst1) = gv1;
            if (gon2) *reinterpret_cast<uint4*>(an + gdst2) = gv2;
        }
        __syncthreads();
    }

    // ---- final dense + sigmoid: 16 threads per batch row ----
    const int r = tid >> 4, m = tid & 15;
    const float4 p0 = *reinterpret_cast<const float4*>(
        (const char*)hbuf + r * 512 + (((2 * m) ^ r) * 16));
    const float4 p1 = *reinterpret_cast<const float4*>(
        (const char*)hbuf + r * 512 + (((2 * m + 1) ^ r) * 16));
    float part = p0.x * Wd[8 * m]     + p0.y * Wd[8 * m + 1]
               + p0.z * Wd[8 * m + 2] + p0.w * Wd[8 * m + 3]
               + p1.x * Wd[8 * m + 4] + p1.y * Wd[8 * m + 5]
               + p1.z * Wd[8 * m + 6] + p1.w * Wd[8 * m + 7];
    part += __shfl_down(part, 8, 16);
    part += __shfl_down(part, 4, 16);
    part += __shfl_down(part, 2, 16);
    part += __shfl_down(part, 1, 16);
    if (m == 0) out[rb + r] = 1.f / (1.f + expf(-(part + bd[0])));
}

// ---------------------------------------------------------------------------
extern "C" void kernel_launch(void* const* d_in, const int* in_sizes, int n_in,
                              void* d_out, int out_size, void* d_ws, size_t ws_size,
                              hipStream_t stream)
{
    (void)in_sizes; (void)n_in; (void)out_size; (void)ws_size;
    const int*   x   = (const int*)  d_in[0];
    const float* emb = (const float*)d_in[1];
    const float* Wxh = (const float*)d_in[2];
    const float* Whh = (const float*)d_in[3];
    const float* bh  = (const float*)d_in[4];
    const float* Wd  = (const float*)d_in[5];
    const float* bd  = (const float*)d_in[6];
    float* out = (float*)d_out;

    // ws: emb_bf16 padded [VOCAB][320] = 32 MB
    unsigned short* embb = (unsigned short*)d_ws;

    const int n_cvt = VOCAB * (EMBP / 8);
    k_embcvt<<<(n_cvt + 255) / 256, 256, 0, stream>>>(emb, embb);
    k_fused<<<BATCH / ROWS, 256, 0, stream>>>(x, embb, Wxh, Whh, bh, Wd, bd, out);
}

// Round 3
// 104.801 us; speedup vs baseline: 5.8247x; 1.6888x over previous
//
#include <hip/hip_runtime.h>
#include <hip/hip_bf16.h>
#include <cstdint>

#define VOCAB 50000
#define EMB   300
#define EMBP  320
#define SEQ   80
#define HID   128
#define BATCH 4096
#define ROWS  16
#define THREADS 512

typedef __attribute__((ext_vector_type(8))) short bf16x8;
typedef __attribute__((ext_vector_type(4))) float f32x4;

static __device__ __forceinline__ unsigned short f32_to_bf16(float f) {
    unsigned int u = __float_as_uint(f);
    unsigned int r = 0x7FFFu + ((u >> 16) & 1u);
    return (unsigned short)((u + r) >> 16);
}
static __device__ __forceinline__ float bf16_to_f32(unsigned short s) {
    return __uint_as_float(((unsigned int)s) << 16);
}
static __device__ __forceinline__ float fast_tanh(float xv) {
    const float e = __expf(2.f * xv);
    return 1.f - 2.f / (e + 1.f);
}

// ---------------------------------------------------------------------------
// k0: emb f32 [VOCAB][300] -> bf16 padded [VOCAB][320], coalesced float4.
// ---------------------------------------------------------------------------
__global__ __launch_bounds__(256) void k_embcvt(const float* __restrict__ emb,
                                                unsigned short* __restrict__ out) {
    const int gid = blockIdx.x * 256 + threadIdx.x;  // over VOCAB*80 ushort4-chunks
    if (gid >= VOCAB * (EMBP / 4)) return;
    const int r  = gid / (EMBP / 4);
    const int c4 = gid % (EMBP / 4);
    ushort4 o; o.x = o.y = o.z = o.w = 0;
    if (c4 < EMB / 4) {  // 75 full float4 per row (300 = 75*16B, rows 16B-aligned)
        const float4 v = *reinterpret_cast<const float4*>(emb + (size_t)r * EMB + c4 * 4);
        o.x = f32_to_bf16(v.x); o.y = f32_to_bf16(v.y);
        o.z = f32_to_bf16(v.z); o.w = f32_to_bf16(v.w);
    }
    *reinterpret_cast<ushort4*>(out + (size_t)r * EMBP + c4 * 4) = o;
}

// ---------------------------------------------------------------------------
// Fused RNN: block = 16 batch rows x 80 steps, 8 waves, wave owns 16 cols.
//   acc = e(t) @ Wxh  (bf16 MFMA, K=320)  +  h(t-1) @ Whh (hi/lo bf16, K=128)
//   h(t) = tanh(acc + bh) -> LDS bf16 hi/lo planes (slot^row XOR swizzle)
// MFMA 16x16x32 frags (m89/m91): A: lane l = A[l&15][8*(l>>4)+j];
//   B: lane l = B[8*(l>>4)+j][l&15]; D: lane l reg r = D[4*(l>>4)+r][l&15].
// Gather pipeline depth 2: LOAD(t+2) issued at step t, written end of t+1.
// ---------------------------------------------------------------------------
__global__ __launch_bounds__(THREADS, 2) void k_fused(
    const int*            __restrict__ x,     // [BATCH][SEQ]
    const unsigned short* __restrict__ embb,  // [VOCAB][EMBP] bf16
    const float*          __restrict__ Wxh,   // [EMB][HID]
    const float*          __restrict__ Whh,   // [HID][HID]
    const float*          __restrict__ bh,    // [HID]
    const float*          __restrict__ Wd,    // [HID]
    const float*          __restrict__ bd,    // [1]
    float*                __restrict__ out)   // [BATCH]
{
    __shared__ __align__(16) unsigned char  Abuf[2][ROWS * EMBP * 2]; // 2 x 10 KB
    __shared__ __align__(16) unsigned short hbf[2][ROWS * HID];       // hi/lo 4 KB each
    __shared__ __align__(16) float          hf[ROWS][HID];            // final step only
    __shared__ int xidx[ROWS * SEQ];

    const int tid  = threadIdx.x;
    const int lane = tid & 63;
    const int wv   = tid >> 6;     // 0..7
    const int r16  = lane & 15;
    const int g    = lane >> 4;    // 0..3
    const int rb   = blockIdx.x * ROWS;

    for (int q = tid; q < ROWS * SEQ; q += THREADS) xidx[q] = x[rb * SEQ + q];
    for (int q = tid; q < 2 * ROWS * HID; q += THREADS) (&hbf[0][0])[q] = 0;

    const int col   = 16 * wv + r16;   // this lane's output column
    const int slw   = col >> 3;        // h-write slot (pre-swizzle)
    const int wbyte = (col & 7) * 2;

    // ---- register-resident Wxh B-fragments ----
    bf16x8 wx[10];
    #pragma unroll
    for (int ks = 0; ks < 10; ++ks) {
        bf16x8 f;
        #pragma unroll
        for (int j = 0; j < 8; ++j) {
            const int kk = 32 * ks + 8 * g + j;
            f[j] = (short)(kk < EMB ? f32_to_bf16(Wxh[kk * HID + col]) : (unsigned short)0);
        }
        wx[ks] = f;
    }
    // ---- register-resident Whh hi/lo B-fragments ----
    bf16x8 whi[4], wlo[4];
    #pragma unroll
    for (int ks = 0; ks < 4; ++ks) {
        bf16x8 fh, fl;
        #pragma unroll
        for (int j = 0; j < 8; ++j) {
            const int kk = 32 * ks + 8 * g + j;
            const float v = Whh[kk * HID + col];
            const unsigned short hi = f32_to_bf16(v);
            fh[j] = (short)hi;
            fl[j] = (short)f32_to_bf16(v - bf16_to_f32(hi));
        }
        whi[ks] = fh; wlo[ks] = fl;
    }
    const float bhv = bh[col];

    // ---- gather chunk assignment: 640 16B-chunks, thread gets 1-2 ----
    const int  q0 = tid;
    const bool on1 = (tid + 512 < 640);
    const int  q1 = on1 ? (tid + 512) : 0;
    const int grow0 = q0 / 40, goff0 = q0 % 40;
    const int grow1 = q1 / 40, goff1 = q1 % 40;
    const int ldst0 = grow0 * 640 + ((goff0 ^ (grow0 & 7)) * 16);
    const int ldst1 = grow1 * 640 + ((goff1 ^ (grow1 & 7)) * 16);

    char* const hb0 = (char*)&hbf[0][0];   // hi plane; lo plane at +4096

    __syncthreads();  // xidx ready

    // prologue: stage tile 0; issue LOAD(tile 1)
    {
        const uint4 t0 = *reinterpret_cast<const uint4*>(
            embb + (size_t)xidx[grow0 * SEQ + 0] * EMBP + goff0 * 8);
        *reinterpret_cast<uint4*>(&Abuf[0][ldst0]) = t0;
        if (on1) {
            const uint4 t1 = *reinterpret_cast<const uint4*>(
                embb + (size_t)xidx[grow1 * SEQ + 0] * EMBP + goff1 * 8);
            *reinterpret_cast<uint4*>(&Abuf[0][ldst1]) = t1;
        }
    }
    uint4 a0 = {}, a1 = {}, b0 = {}, b1 = {};
    a0 = *reinterpret_cast<const uint4*>(
        embb + (size_t)xidx[grow0 * SEQ + 1] * EMBP + goff0 * 8);
    if (on1) a1 = *reinterpret_cast<const uint4*>(
        embb + (size_t)xidx[grow1 * SEQ + 1] * EMBP + goff1 * 8);
    __syncthreads();  // tile0 + h(-1)=0 visible

    const f32x4 z4 = {0.f, 0.f, 0.f, 0.f};

#define STEP(T, BUF, CUR0, CUR1, NXT0, NXT1)                                      \
    {                                                                             \
        if ((T) + 2 < SEQ) {                                                      \
            NXT0 = *reinterpret_cast<const uint4*>(                               \
                embb + (size_t)xidx[grow0 * SEQ + (T) + 2] * EMBP + goff0 * 8);   \
            if (on1) NXT1 = *reinterpret_cast<const uint4*>(                      \
                embb + (size_t)xidx[grow1 * SEQ + (T) + 2] * EMBP + goff1 * 8);   \
        }                                                                         \
        f32x4 accx = z4, acch = z4;                                               \
        const unsigned char* ab = &Abuf[BUF][0];                                  \
        _Pragma("unroll")                                                         \
        for (int ks = 0; ks < 10; ++ks) {                                         \
            const bf16x8 ae = *reinterpret_cast<const bf16x8*>(                   \
                ab + r16 * 640 + (((4 * ks + g) ^ (r16 & 7)) * 16));              \
            accx = __builtin_amdgcn_mfma_f32_16x16x32_bf16(ae, wx[ks], accx,      \
                                                           0, 0, 0);              \
        }                                                                         \
        _Pragma("unroll")                                                         \
        for (int ks = 0; ks < 4; ++ks) {                                          \
            const int sl = ((4 * ks + g) ^ r16) * 16;                             \
            const bf16x8 ah = *reinterpret_cast<const bf16x8*>(                   \
                hb0 + r16 * 256 + sl);                                            \
            const bf16x8 al = *reinterpret_cast<const bf16x8*>(                   \
                hb0 + 4096 + r16 * 256 + sl);                                     \
            acch = __builtin_amdgcn_mfma_f32_16x16x32_bf16(ah, whi[ks], acch,     \
                                                           0, 0, 0);              \
            acch = __builtin_amdgcn_mfma_f32_16x16x32_bf16(al, whi[ks], acch,     \
                                                           0, 0, 0);              \
            acch = __builtin_amdgcn_mfma_f32_16x16x32_bf16(ah, wlo[ks], acch,     \
                                                           0, 0, 0);              \
        }                                                                         \
        __syncthreads(); /* reads of h(T-1) and tile T complete */                \
        if ((T) + 1 < SEQ) {                                                      \
            *reinterpret_cast<uint4*>(&Abuf[(BUF) ^ 1][ldst0]) = CUR0;            \
            if (on1) *reinterpret_cast<uint4*>(&Abuf[(BUF) ^ 1][ldst1]) = CUR1;   \
        }                                                                         \
        _Pragma("unroll")                                                         \
        for (int reg = 0; reg < 4; ++reg) {                                       \
            const int rr = 4 * g + reg;                                           \
            const float v = fast_tanh(accx[reg] + acch[reg] + bhv);               \
            const unsigned short hi = f32_to_bf16(v);                             \
            const unsigned short lo = f32_to_bf16(v - bf16_to_f32(hi));           \
            char* p = hb0 + rr * 256 + ((slw ^ rr) * 16) + wbyte;                 \
            *reinterpret_cast<unsigned short*>(p) = hi;                           \
            *reinterpret_cast<unsigned short*>(p + 4096) = lo;                    \
            if ((T) == SEQ - 1) hf[rr][col] = v;                                  \
        }                                                                         \
        __syncthreads(); /* h(T) + tile T+1 visible */                            \
    }

    for (int t = 0; t < SEQ; t += 2) {
        STEP(t,     0, a0, a1, b0, b1);
        STEP(t + 1, 1, b0, b1, a0, a1);
    }
#undef STEP

    // ---- final dense + sigmoid: 32 threads per batch row ----
    const int r = tid >> 5;     // 0..15
    const int m = tid & 31;     // 0..31
    const float4 hv = *reinterpret_cast<const float4*>(&hf[r][4 * m]);
    const float4 wd = *reinterpret_cast<const float4*>(&Wd[4 * m]);
    float part = hv.x * wd.x + hv.y * wd.y + hv.z * wd.z + hv.w * wd.w;
    part += __shfl_down(part, 16, 32);
    part += __shfl_down(part, 8, 32);
    part += __shfl_down(part, 4, 32);
    part += __shfl_down(part, 2, 32);
    part += __shfl_down(part, 1, 32);
    if (m == 0) out[rb + r] = 1.f / (1.f + expf(-(part + bd[0])));
}

// ---------------------------------------------------------------------------
extern "C" void kernel_launch(void* const* d_in, const int* in_sizes, int n_in,
                              void* d_out, int out_size, void* d_ws, size_t ws_size,
                              hipStream_t stream)
{
    (void)in_sizes; (void)n_in; (void)out_size; (void)ws_size;
    const int*   x   = (const int*)  d_in[0];
    const float* emb = (const float*)d_in[1];
    const float* Wxh = (const float*)d_in[2];
    const float* Whh = (const float*)d_in[3];
    const float* bh  = (const float*)d_in[4];
    const float* Wd  = (const float*)d_in[5];
    const float* bd  = (const float*)d_in[6];
    float* out = (float*)d_out;

    unsigned short* embb = (unsigned short*)d_ws;  // bf16 table, 32 MB

    const int n_cvt = VOCAB * (EMBP / 4);
    k_embcvt<<<(n_cvt + 255) / 256, 256, 0, stream>>>(emb, embb);
    k_fused<<<BATCH / ROWS, THREADS, 0, stream>>>(x, embb, Wxh, Whh, bh, Wd, bd, out);
}

// Round 4
// 98.417 us; speedup vs baseline: 6.2025x; 1.0649x over previous
//
#include <hip/hip_runtime.h>
#include <hip/hip_fp16.h>
#include <cstdint>

#define VOCAB 50000
#define EMB   300
#define EMBP  320
#define SEQ   80
#define HID   128
#define BATCH 4096
#define ROWS  16
#define THREADS 256

typedef __attribute__((ext_vector_type(8))) _Float16 f16x8;
typedef __attribute__((ext_vector_type(4))) float    f32x4;

static __device__ __forceinline__ float fast_tanh(float xv) {
    const float e = __expf(2.f * xv);
    return 1.f - 2.f / (e + 1.f);
}

// ---------------------------------------------------------------------------
// k0: emb f32 [VOCAB][300] -> fp16 padded [VOCAB][320] (zeros at k >= 300)
// ---------------------------------------------------------------------------
__global__ __launch_bounds__(256) void k_embcvt(const float* __restrict__ emb,
                                                _Float16* __restrict__ out) {
    const int gid = blockIdx.x * 256 + threadIdx.x;
    if (gid >= VOCAB * (EMBP / 4)) return;
    const int r  = gid / (EMBP / 4);
    const int c4 = gid % (EMBP / 4);
    ushort4 o; o.x = o.y = o.z = o.w = 0;
    if (c4 < EMB / 4) {
        const float4 v = *reinterpret_cast<const float4*>(emb + (size_t)r * EMB + c4 * 4);
        _Float16 a = (_Float16)v.x, b = (_Float16)v.y,
                 c = (_Float16)v.z, d = (_Float16)v.w;
        o.x = *(unsigned short*)&a; o.y = *(unsigned short*)&b;
        o.z = *(unsigned short*)&c; o.w = *(unsigned short*)&d;
    }
    *reinterpret_cast<ushort4*>((unsigned short*)out + (size_t)r * EMBP + c4 * 4) = o;
}

// ---------------------------------------------------------------------------
// Fused RNN, fp16 MFMA. Block = 16 batch rows x 80 steps, 4 waves,
// wave owns 32 output cols (2 16-col tiles) -> A-frags reused 2x.
//   acc = e(t) @ Wxh (K=320) + h(t-1) @ Whh (K=128); h(t)=tanh(acc+bh)
// h and A double-buffered in LDS; ONE raw barrier per step (lgkmcnt only,
// no vmcnt drain -> gather prefetch stays in flight across barriers).
// MFMA 16x16x32 frags: A: lane l = A[l&15][8*(l>>4)+j];
//   B: lane l = B[8*(l>>4)+j][l&15]; D: lane l reg r = D[4*(l>>4)+r][l&15].
// ---------------------------------------------------------------------------
__global__ __launch_bounds__(THREADS, 1) void k_fused(
    const int*      __restrict__ x,     // [BATCH][SEQ]
    const _Float16* __restrict__ embb,  // [VOCAB][EMBP] fp16
    const float*    __restrict__ Wxh,   // [EMB][HID]
    const float*    __restrict__ Whh,   // [HID][HID]
    const float*    __restrict__ bh,    // [HID]
    const float*    __restrict__ Wd,    // [HID]
    const float*    __restrict__ bd,    // [1]
    float*          __restrict__ out)   // [BATCH]
{
    __shared__ __align__(16) unsigned char Abuf[2][ROWS * EMBP * 2]; // 2 x 10 KB
    __shared__ __align__(16) unsigned char Hbuf[2][ROWS * HID * 2];  // 2 x 4 KB fp16
    __shared__ __align__(16) float         hf[ROWS][HID];            // 8 KB
    __shared__ int xidx[ROWS * SEQ];                                  // 5 KB

    const int tid  = threadIdx.x;
    const int lane = tid & 63;
    const int wv   = tid >> 6;     // 0..3
    const int r16  = lane & 15;
    const int g    = lane >> 4;    // 0..3
    const int rb   = blockIdx.x * ROWS;

    for (int q = tid; q < ROWS * SEQ; q += THREADS) xidx[q] = x[rb * SEQ + q];
    {   // zero h parity-0 buffer (16 B per thread covers 4096 B)
        uint4 z = {};
        *reinterpret_cast<uint4*>(&Hbuf[0][tid * 16 & (ROWS * HID * 2 - 1)]) = z;
    }

    const int col0 = 32 * wv + r16;
    const int col1 = col0 + 16;

    // ---- t-invariant LDS offsets ----
    int a_off[10], h_off[4];
    #pragma unroll
    for (int ks = 0; ks < 10; ++ks)
        a_off[ks] = r16 * 640 + (((4 * ks + g) ^ (r16 & 7)) * 16);
    #pragma unroll
    for (int ks = 0; ks < 4; ++ks)
        h_off[ks] = r16 * 256 + (((4 * ks + g) ^ r16) * 16);
    int w_off0[4], w_off1[4];
    #pragma unroll
    for (int r = 0; r < 4; ++r) {
        const int rr = 4 * g + r;
        w_off0[r] = rr * 256 + (((col0 >> 3) ^ rr) * 16) + (col0 & 7) * 2;
        w_off1[r] = rr * 256 + (((col1 >> 3) ^ rr) * 16) + (col1 & 7) * 2;
    }

    // ---- register-resident weight B-fragments (fp16) ----
    f16x8 wx0[10], wx1[10];
    #pragma unroll
    for (int ks = 0; ks < 10; ++ks) {
        f16x8 f0, f1;
        #pragma unroll
        for (int j = 0; j < 8; ++j) {
            const int kk = 32 * ks + 8 * g + j;
            f0[j] = (_Float16)(kk < EMB ? Wxh[kk * HID + col0] : 0.f);
            f1[j] = (_Float16)(kk < EMB ? Wxh[kk * HID + col1] : 0.f);
        }
        wx0[ks] = f0; wx1[ks] = f1;
    }
    f16x8 wh0[4], wh1[4];
    #pragma unroll
    for (int ks = 0; ks < 4; ++ks) {
        f16x8 f0, f1;
        #pragma unroll
        for (int j = 0; j < 8; ++j) {
            const int kk = 32 * ks + 8 * g + j;
            f0[j] = (_Float16)Whh[kk * HID + col0];
            f1[j] = (_Float16)Whh[kk * HID + col1];
        }
        wh0[ks] = f0; wh1[ks] = f1;
    }
    const float bhv0 = bh[col0];
    const float bhv1 = bh[col1];

    // ---- gather chunk assignment: 640 16B chunks over 256 threads ----
    const int  q0 = tid, q1 = tid + 256, q2 = tid + 512;
    const bool on2 = (tid < 128);              // waves 0,1 uniformly
    const int grow0 = q0 / 40, goff0 = q0 % 40;
    const int grow1 = q1 / 40, goff1 = q1 % 40;
    const int grow2 = (on2 ? q2 : 0) / 40, goff2 = (on2 ? q2 : 0) % 40;
    const int ldst0 = grow0 * 640 + ((goff0 ^ (grow0 & 7)) * 16);
    const int ldst1 = grow1 * 640 + ((goff1 ^ (grow1 & 7)) * 16);
    const int ldst2 = grow2 * 640 + ((goff2 ^ (grow2 & 7)) * 16);

    __syncthreads();  // xidx + h0 ready (full sync fine in prologue)

    // prologue: stage tile 0 directly; issue loads for tile 1
    {
        const uint4 t0 = *reinterpret_cast<const uint4*>(
            (const unsigned short*)embb + (size_t)xidx[grow0 * SEQ] * EMBP + goff0 * 8);
        const uint4 t1 = *reinterpret_cast<const uint4*>(
            (const unsigned short*)embb + (size_t)xidx[grow1 * SEQ] * EMBP + goff1 * 8);
        *reinterpret_cast<uint4*>(&Abuf[0][ldst0]) = t0;
        *reinterpret_cast<uint4*>(&Abuf[0][ldst1]) = t1;
        if (on2) {
            const uint4 t2 = *reinterpret_cast<const uint4*>(
                (const unsigned short*)embb + (size_t)xidx[grow2 * SEQ] * EMBP + goff2 * 8);
            *reinterpret_cast<uint4*>(&Abuf[0][ldst2]) = t2;
        }
    }
    uint4 cur0, cur1, cur2 = {}, nxt0 = {}, nxt1 = {}, nxt2 = {};
    cur0 = *reinterpret_cast<const uint4*>(
        (const unsigned short*)embb + (size_t)xidx[grow0 * SEQ + 1] * EMBP + goff0 * 8);
    cur1 = *reinterpret_cast<const uint4*>(
        (const unsigned short*)embb + (size_t)xidx[grow1 * SEQ + 1] * EMBP + goff1 * 8);
    if (on2) cur2 = *reinterpret_cast<const uint4*>(
        (const unsigned short*)embb + (size_t)xidx[grow2 * SEQ + 1] * EMBP + goff2 * 8);

    asm volatile("s_waitcnt lgkmcnt(0)" ::: "memory");
    __builtin_amdgcn_s_barrier();
    __builtin_amdgcn_sched_barrier(0);

    const f32x4 z4 = {0.f, 0.f, 0.f, 0.f};

#define STEP(T, P, CUR0, CUR1, CUR2, NXT0, NXT1, NXT2)                             \
    {                                                                              \
        if ((T) + 2 < SEQ) {                                                       \
            NXT0 = *reinterpret_cast<const uint4*>((const unsigned short*)embb +   \
                (size_t)xidx[grow0 * SEQ + (T) + 2] * EMBP + goff0 * 8);           \
            NXT1 = *reinterpret_cast<const uint4*>((const unsigned short*)embb +   \
                (size_t)xidx[grow1 * SEQ + (T) + 2] * EMBP + goff1 * 8);           \
            if (on2) NXT2 = *reinterpret_cast<const uint4*>(                       \
                (const unsigned short*)embb +                                      \
                (size_t)xidx[grow2 * SEQ + (T) + 2] * EMBP + goff2 * 8);           \
        }                                                                          \
        const unsigned char* ab = &Abuf[P][0];                                     \
        const unsigned char* hb = &Hbuf[P][0];                                     \
        f32x4 xA0 = z4, xB0 = z4, xA1 = z4, xB1 = z4;                              \
        _Pragma("unroll")                                                          \
        for (int ks = 0; ks < 10; ks += 2) {                                       \
            const f16x8 aeA = *reinterpret_cast<const f16x8*>(ab + a_off[ks]);     \
            const f16x8 aeB = *reinterpret_cast<const f16x8*>(ab + a_off[ks + 1]); \
            xA0 = __builtin_amdgcn_mfma_f32_16x16x32_f16(aeA, wx0[ks], xA0, 0,0,0);\
            xA1 = __builtin_amdgcn_mfma_f32_16x16x32_f16(aeA, wx1[ks], xA1, 0,0,0);\
            xB0 = __builtin_amdgcn_mfma_f32_16x16x32_f16(aeB, wx0[ks+1], xB0,0,0,0);\
            xB1 = __builtin_amdgcn_mfma_f32_16x16x32_f16(aeB, wx1[ks+1], xB1,0,0,0);\
        }                                                                          \
        const f16x8 h0 = *reinterpret_cast<const f16x8*>(hb + h_off[0]);           \
        const f16x8 h1 = *reinterpret_cast<const f16x8*>(hb + h_off[1]);           \
        const f16x8 h2 = *reinterpret_cast<const f16x8*>(hb + h_off[2]);           \
        const f16x8 h3 = *reinterpret_cast<const f16x8*>(hb + h_off[3]);           \
        xA0 = __builtin_amdgcn_mfma_f32_16x16x32_f16(h0, wh0[0], xA0, 0, 0, 0);    \
        xB0 = __builtin_amdgcn_mfma_f32_16x16x32_f16(h1, wh0[1], xB0, 0, 0, 0);    \
        xA1 = __builtin_amdgcn_mfma_f32_16x16x32_f16(h0, wh1[0], xA1, 0, 0, 0);    \
        xB1 = __builtin_amdgcn_mfma_f32_16x16x32_f16(h1, wh1[1], xB1, 0, 0, 0);    \
        xA0 = __builtin_amdgcn_mfma_f32_16x16x32_f16(h2, wh0[2], xA0, 0, 0, 0);    \
        xB0 = __builtin_amdgcn_mfma_f32_16x16x32_f16(h3, wh0[3], xB0, 0, 0, 0);    \
        xA1 = __builtin_amdgcn_mfma_f32_16x16x32_f16(h2, wh1[2], xA1, 0, 0, 0);    \
        xB1 = __builtin_amdgcn_mfma_f32_16x16x32_f16(h3, wh1[3], xB1, 0, 0, 0);    \
        /* stage tile T+1 into A[P^1] (read at T-1 finished before last barrier)*/ \
        if ((T) + 1 < SEQ) {                                                       \
            *reinterpret_cast<uint4*>(&Abuf[(P) ^ 1][ldst0]) = CUR0;               \
            *reinterpret_cast<uint4*>(&Abuf[(P) ^ 1][ldst1]) = CUR1;               \
            if (on2) *reinterpret_cast<uint4*>(&Abuf[(P) ^ 1][ldst2]) = CUR2;      \
        }                                                                          \
        unsigned char* hw = &Hbuf[(P) ^ 1][0];                                     \
        _Pragma("unroll")                                                          \
        for (int r = 0; r < 4; ++r) {                                              \
            const float v0 = fast_tanh(xA0[r] + xB0[r] + bhv0);                    \
            const float v1 = fast_tanh(xA1[r] + xB1[r] + bhv1);                    \
            *reinterpret_cast<_Float16*>(hw + w_off0[r]) = (_Float16)v0;           \
            *reinterpret_cast<_Float16*>(hw + w_off1[r]) = (_Float16)v1;           \
            if ((T) == SEQ - 1) {                                                  \
                hf[4 * g + r][col0] = v0;                                          \
                hf[4 * g + r][col1] = v1;                                          \
            }                                                                      \
        }                                                                          \
        asm volatile("s_waitcnt lgkmcnt(0)" ::: "memory");                         \
        __builtin_amdgcn_s_barrier();                                              \
        __builtin_amdgcn_sched_barrier(0);                                         \
    }

    for (int t = 0; t < SEQ; t += 2) {
        STEP(t,     0, cur0, cur1, cur2, nxt0, nxt1, nxt2);
        STEP(t + 1, 1, nxt0, nxt1, nxt2, cur0, cur1, cur2);
    }
#undef STEP

    // ---- final dense + sigmoid: 16 threads per batch row ----
    const int r = tid >> 4, m = tid & 15;
    const float4 p0 = *reinterpret_cast<const float4*>(&hf[r][8 * m]);
    const float4 p1 = *reinterpret_cast<const float4*>(&hf[r][8 * m + 4]);
    const float4 w0 = *reinterpret_cast<const float4*>(&Wd[8 * m]);
    const float4 w1 = *reinterpret_cast<const float4*>(&Wd[8 * m + 4]);
    float part = p0.x * w0.x + p0.y * w0.y + p0.z * w0.z + p0.w * w0.w
               + p1.x * w1.x + p1.y * w1.y + p1.z * w1.z + p1.w * w1.w;
    part += __shfl_down(part, 8, 16);
    part += __shfl_down(part, 4, 16);
    part += __shfl_down(part, 2, 16);
    part += __shfl_down(part, 1, 16);
    if (m == 0) out[rb + r] = 1.f / (1.f + expf(-(part + bd[0])));
}

// ---------------------------------------------------------------------------
extern "C" void kernel_launch(void* const* d_in, const int* in_sizes, int n_in,
                              void* d_out, int out_size, void* d_ws, size_t ws_size,
                              hipStream_t stream)
{
    (void)in_sizes; (void)n_in; (void)out_size; (void)ws_size;
    const int*   x   = (const int*)  d_in[0];
    const float* emb = (const float*)d_in[1];
    const float* Wxh = (const float*)d_in[2];
    const float* Whh = (const float*)d_in[3];
    const float* bh  = (const float*)d_in[4];
    const float* Wd  = (const float*)d_in[5];
    const float* bd  = (const float*)d_in[6];
    float* out = (float*)d_out;

    _Float16* embb = (_Float16*)d_ws;  // fp16 table, 32 MB

    const int n_cvt = VOCAB * (EMBP / 4);
    k_embcvt<<<(n_cvt + 255) / 256, 256, 0, stream>>>(emb, embb);
    k_fused<<<BATCH / ROWS, THREADS, 0, stream>>>(x, embb, Wxh, Whh, bh, Wd, bd, out);
}

// Round 5
// 82.673 us; speedup vs baseline: 7.3837x; 1.1904x over previous
//
#include <hip/hip_runtime.h>
#include <hip/hip_fp16.h>
#include <cstdint>

#define VOCAB 50000
#define EMB   300
#define EMBP  320
#define SEQ   80
#define HID   128
#define BATCH 4096
#define ROWS  16
#define THREADS 512

typedef __attribute__((ext_vector_type(8))) _Float16 f16x8;
typedef __attribute__((ext_vector_type(4))) float    f32x4;

static __device__ __forceinline__ float fast_tanh(float xv) {
    const float e = __expf(2.f * xv);
    return 1.f - 2.f / (e + 1.f);
}
static __device__ __forceinline__ float f16b2f(unsigned short u) {
    _Float16 h;
    __builtin_memcpy(&h, &u, 2);
    return (float)h;
}

// ---------------------------------------------------------------------------
// k0: emb f32 [VOCAB][300] -> fp16 padded [VOCAB][320] (zeros at k >= 300)
// ---------------------------------------------------------------------------
__global__ __launch_bounds__(256) void k_embcvt(const float* __restrict__ emb,
                                                _Float16* __restrict__ out) {
    const int gid = blockIdx.x * 256 + threadIdx.x;
    if (gid >= VOCAB * (EMBP / 4)) return;
    const int r  = gid / (EMBP / 4);
    const int c4 = gid % (EMBP / 4);
    ushort4 o; o.x = o.y = o.z = o.w = 0;
    if (c4 < EMB / 4) {
        const float4 v = *reinterpret_cast<const float4*>(emb + (size_t)r * EMB + c4 * 4);
        _Float16 a = (_Float16)v.x, b = (_Float16)v.y,
                 c = (_Float16)v.z, d = (_Float16)v.w;
        o.x = *(unsigned short*)&a; o.y = *(unsigned short*)&b;
        o.z = *(unsigned short*)&c; o.w = *(unsigned short*)&d;
    }
    *reinterpret_cast<ushort4*>((unsigned short*)out + (size_t)r * EMBP + c4 * 4) = o;
}

// ---------------------------------------------------------------------------
// Fused RNN, fp16 MFMA. Block = 16 batch rows x 80 steps; 8 waves (2/SIMD),
// wave owns 16 output cols.  Per wave/step: 10 A-reads + 4 h-reads (b128),
// 14 MFMA, tanh, h-write.  One raw barrier per step (lgkmcnt-only drain).
// Step order: ds_write(prefetched tile) FIRST, then issue next gather loads
// -> any vmcnt wait at the write targets loads issued a full step earlier.
// MFMA 16x16x32 frags: A: lane l = A[l&15][8*(l>>4)+j];
//   B: lane l = B[8*(l>>4)+j][l&15]; D: lane l reg r = D[4*(l>>4)+r][l&15].
// ---------------------------------------------------------------------------
__global__ __launch_bounds__(THREADS, 2) void k_fused(
    const int*      __restrict__ x,     // [BATCH][SEQ]
    const _Float16* __restrict__ embb,  // [VOCAB][EMBP] fp16
    const float*    __restrict__ Wxh,   // [EMB][HID]
    const float*    __restrict__ Whh,   // [HID][HID]
    const float*    __restrict__ bh,    // [HID]
    const float*    __restrict__ Wd,    // [HID]
    const float*    __restrict__ bd,    // [1]
    float*          __restrict__ out)   // [BATCH]
{
    __shared__ __align__(16) unsigned char Abuf[2][ROWS * EMBP * 2]; // 2 x 10 KB
    __shared__ __align__(16) unsigned char Hbuf[2][ROWS * HID * 2];  // 2 x 4 KB fp16
    __shared__ int xidx[ROWS * SEQ];                                  // 5 KB

    const int tid  = threadIdx.x;
    const int lane = tid & 63;
    const int wv   = tid >> 6;     // 0..7
    const int r16  = lane & 15;
    const int g    = lane >> 4;    // 0..3
    const int rb   = blockIdx.x * ROWS;

    for (int q = tid; q < ROWS * SEQ; q += THREADS) xidx[q] = x[rb * SEQ + q];
    if (tid < 256) {  // zero h parity-0 buffer (4 KB)
        uint4 z = {};
        *reinterpret_cast<uint4*>(&Hbuf[0][tid * 16]) = z;
    }

    const int col = 16 * wv + r16;   // this lane's output column

    // ---- t-invariant LDS offsets ----
    int a_off[10], h_off[4], w_off[4];
    #pragma unroll
    for (int ks = 0; ks < 10; ++ks)
        a_off[ks] = r16 * 640 + (((4 * ks + g) ^ (r16 & 7)) * 16);
    #pragma unroll
    for (int ks = 0; ks < 4; ++ks)
        h_off[ks] = r16 * 256 + (((4 * ks + g) ^ r16) * 16);
    #pragma unroll
    for (int r = 0; r < 4; ++r) {
        const int rr = 4 * g + r;
        w_off[r] = rr * 256 + (((col >> 3) ^ rr) * 16) + (col & 7) * 2;
    }

    // ---- register-resident weight B-fragments (fp16) ----
    f16x8 wx[10];
    #pragma unroll
    for (int ks = 0; ks < 10; ++ks) {
        f16x8 f;
        #pragma unroll
        for (int j = 0; j < 8; ++j) {
            const int kk = 32 * ks + 8 * g + j;
            f[j] = (_Float16)(kk < EMB ? Wxh[kk * HID + col] : 0.f);
        }
        wx[ks] = f;
    }
    f16x8 wh[4];
    #pragma unroll
    for (int ks = 0; ks < 4; ++ks) {
        f16x8 f;
        #pragma unroll
        for (int j = 0; j < 8; ++j) {
            const int kk = 32 * ks + 8 * g + j;
            f[j] = (_Float16)Whh[kk * HID + col];
        }
        wh[ks] = f;
    }
    const float bhv = bh[col];

    // ---- gather chunk assignment: 640 16B chunks over 512 threads ----
    const int  q0 = tid;
    const bool on1 = (tid < 128);              // waves 0,1 take a 2nd chunk
    const int  q1 = on1 ? (tid + 512) : 0;
    const int grow0 = q0 / 40, goff0 = q0 % 40;
    const int grow1 = q1 / 40, goff1 = q1 % 40;
    const int ldst0 = grow0 * 640 + ((goff0 ^ (grow0 & 7)) * 16);
    const int ldst1 = grow1 * 640 + ((goff1 ^ (grow1 & 7)) * 16);

    char* const hb0 = (char*)&Hbuf[0][0];

    __syncthreads();  // xidx + h0 ready

    // prologue: stage tile 0 directly; issue loads for tile 1
    {
        const uint4 t0 = *reinterpret_cast<const uint4*>(
            (const unsigned short*)embb + (size_t)xidx[grow0 * SEQ] * EMBP + goff0 * 8);
        *reinterpret_cast<uint4*>(&Abuf[0][ldst0]) = t0;
        if (on1) {
            const uint4 t1 = *reinterpret_cast<const uint4*>(
                (const unsigned short*)embb + (size_t)xidx[grow1 * SEQ] * EMBP + goff1 * 8);
            *reinterpret_cast<uint4*>(&Abuf[0][ldst1]) = t1;
        }
    }
    uint4 cur0, cur1 = {}, nxt0 = {}, nxt1 = {};
    cur0 = *reinterpret_cast<const uint4*>(
        (const unsigned short*)embb + (size_t)xidx[grow0 * SEQ + 1] * EMBP + goff0 * 8);
    if (on1) cur1 = *reinterpret_cast<const uint4*>(
        (const unsigned short*)embb + (size_t)xidx[grow1 * SEQ + 1] * EMBP + goff1 * 8);

    asm volatile("s_waitcnt lgkmcnt(0)" ::: "memory");
    __builtin_amdgcn_s_barrier();
    __builtin_amdgcn_sched_barrier(0);

    const f32x4 z4 = {0.f, 0.f, 0.f, 0.f};

#define STEP(T, P, CUR0, CUR1, NXT0, NXT1)                                         \
    {                                                                              \
        /* 1. write prefetched tile T+1 (loaded a full step ago) */                \
        if ((T) + 1 < SEQ) {                                                       \
            *reinterpret_cast<uint4*>(&Abuf[(P) ^ 1][ldst0]) = CUR0;               \
            if (on1) *reinterpret_cast<uint4*>(&Abuf[(P) ^ 1][ldst1]) = CUR1;      \
        }                                                                          \
        /* 2. issue gather loads for tile T+2 */                                   \
        if ((T) + 2 < SEQ) {                                                       \
            NXT0 = *reinterpret_cast<const uint4*>((const unsigned short*)embb +   \
                (size_t)xidx[grow0 * SEQ + (T) + 2] * EMBP + goff0 * 8);           \
            if (on1) NXT1 = *reinterpret_cast<const uint4*>(                       \
                (const unsigned short*)embb +                                      \
                (size_t)xidx[grow1 * SEQ + (T) + 2] * EMBP + goff1 * 8);           \
        }                                                                          \
        /* 3. compute: two interleaved acc chains */                               \
        const unsigned char* ab = &Abuf[P][0];                                     \
        const unsigned char* hb = &Hbuf[P][0];                                     \
        f32x4 accA = z4, accB = z4;                                                \
        _Pragma("unroll")                                                          \
        for (int ks = 0; ks < 10; ks += 2) {                                       \
            const f16x8 aeA = *reinterpret_cast<const f16x8*>(ab + a_off[ks]);     \
            const f16x8 aeB = *reinterpret_cast<const f16x8*>(ab + a_off[ks + 1]); \
            accA = __builtin_amdgcn_mfma_f32_16x16x32_f16(aeA, wx[ks], accA,0,0,0);\
            accB = __builtin_amdgcn_mfma_f32_16x16x32_f16(aeB, wx[ks+1],accB,0,0,0);\
        }                                                                          \
        const f16x8 h0 = *reinterpret_cast<const f16x8*>(hb + h_off[0]);           \
        const f16x8 h1 = *reinterpret_cast<const f16x8*>(hb + h_off[1]);           \
        const f16x8 h2 = *reinterpret_cast<const f16x8*>(hb + h_off[2]);           \
        const f16x8 h3 = *reinterpret_cast<const f16x8*>(hb + h_off[3]);           \
        accA = __builtin_amdgcn_mfma_f32_16x16x32_f16(h0, wh[0], accA, 0, 0, 0);   \
        accB = __builtin_amdgcn_mfma_f32_16x16x32_f16(h1, wh[1], accB, 0, 0, 0);   \
        accA = __builtin_amdgcn_mfma_f32_16x16x32_f16(h2, wh[2], accA, 0, 0, 0);   \
        accB = __builtin_amdgcn_mfma_f32_16x16x32_f16(h3, wh[3], accB, 0, 0, 0);   \
        /* 4. tanh + h write */                                                    \
        unsigned char* hw = &Hbuf[(P) ^ 1][0];                                     \
        _Pragma("unroll")                                                          \
        for (int r = 0; r < 4; ++r) {                                              \
            const float v = fast_tanh(accA[r] + accB[r] + bhv);                    \
            *reinterpret_cast<_Float16*>(hw + w_off[r]) = (_Float16)v;             \
        }                                                                          \
        asm volatile("s_waitcnt lgkmcnt(0)" ::: "memory");                         \
        __builtin_amdgcn_s_barrier();                                              \
        __builtin_amdgcn_sched_barrier(0);                                         \
    }

    for (int t = 0; t < SEQ; t += 2) {
        STEP(t,     0, cur0, cur1, nxt0, nxt1);
        STEP(t + 1, 1, nxt0, nxt1, cur0, cur1);
    }
#undef STEP

    // ---- final dense + sigmoid from Hbuf[0] (fp16 h after step 79) ----
    // 32 threads per batch row; each handles 4 consecutive cols.
    const int r = tid >> 5;     // 0..15
    const int m = tid & 31;     // 0..31, cols 4m..4m+3
    const int base = r * 256 + ((((m >> 1)) ^ r) * 16) + ((4 * m) & 7) * 2;
    const ushort4 hu = *reinterpret_cast<const ushort4*>(hb0 + base);
    const float4  wd = *reinterpret_cast<const float4*>(&Wd[4 * m]);
    float part = f16b2f(hu.x) * wd.x + f16b2f(hu.y) * wd.y
               + f16b2f(hu.z) * wd.z + f16b2f(hu.w) * wd.w;
    part += __shfl_down(part, 16, 32);
    part += __shfl_down(part, 8, 32);
    part += __shfl_down(part, 4, 32);
    part += __shfl_down(part, 2, 32);
    part += __shfl_down(part, 1, 32);
    if (m == 0) out[rb + r] = 1.f / (1.f + expf(-(part + bd[0])));
}

// ---------------------------------------------------------------------------
extern "C" void kernel_launch(void* const* d_in, const int* in_sizes, int n_in,
                              void* d_out, int out_size, void* d_ws, size_t ws_size,
                              hipStream_t stream)
{
    (void)in_sizes; (void)n_in; (void)out_size; (void)ws_size;
    const int*   x   = (const int*)  d_in[0];
    const float* emb = (const float*)d_in[1];
    const float* Wxh = (const float*)d_in[2];
    const float* Whh = (const float*)d_in[3];
    const float* bh  = (const float*)d_in[4];
    const float* Wd  = (const float*)d_in[5];
    const float* bd  = (const float*)d_in[6];
    float* out = (float*)d_out;

    _Float16* embb = (_Float16*)d_ws;  // fp16 table, 32 MB

    const int n_cvt = VOCAB * (EMBP / 4);
    k_embcvt<<<(n_cvt + 255) / 256, 256, 0, stream>>>(emb, embb);
    k_fused<<<BATCH / ROWS, THREADS, 0, stream>>>(x, embb, Wxh, Whh, bh, Wd, bd, out);
}